// Round 6
// baseline (1295.167 us; speedup 1.0000x reference)
//
#include <hip/hip_runtime.h>

// GCN 2-layer forward on MI355X (gfx950).
// out = A @ relu(A @ (x@W1) + b1) @ W2 + b2   (A = weighted edge aggregation)
// R13: megakernel with MANUAL grid barrier (cooperative API abandoned).
//  - R12 (hipLaunchCooperativeKernel) killed the container twice. Same fused
//    structure, but grid-sync is now a sense-reversing barrier built on
//    __hip_atomic_* AGENT-scope acquire/release -- the same primitives the
//    scan lookback has used correctly since R8. Plain launch, capturable.
//  - Co-residency by construction: GRID=1024=256CUx4, launch_bounds(256,4)
//    (VGPR<=128), LDS 35.9KB*4=144KB<=160KB, 16 waves/CU. Uniform blocks ->
//    no fragmentation -> all resident -> barrier cannot starve.
//  - All spins have bounded timeouts (fail the test, not the container);
//    scatter pos clamped so the failure mode cannot wild-write.
//  - 2 dispatches: init_bar (zero barrier+gflag) then mega.

#define F0 512
#define F1 128
#define F2 40
#define F2P 48   // padded S2 row (bf16)
#define GRID 1024
#define GSZ (GRID*256)
#define SPIN_CAP 200000   // ~10ms of s_sleep(2); never hit when co-resident

typedef short bf16x8 __attribute__((ext_vector_type(8)));
typedef float f32x4 __attribute__((ext_vector_type(4)));

// accurate RNE bf16 (weights, once per call)
static __device__ __forceinline__ unsigned short f2b(float f){
    union { float f; unsigned int u; } x; x.f = f;
    unsigned int u = x.u;
    unsigned int r = (u + 0x7fffu + ((u >> 16) & 1u)) >> 16;
    return (unsigned short)r;
}
// fast round-half-up bf16 (activations)
static __device__ __forceinline__ unsigned short f2b_fast(float f){
    return (unsigned short)((__float_as_uint(f) + 0x8000u) >> 16);
}
static __device__ __forceinline__ unsigned int pack2(float a, float b){
    unsigned int ua = __float_as_uint(a) + 0x8000u;
    unsigned int ub = __float_as_uint(b) + 0x8000u;
    return __builtin_amdgcn_perm(ub, ua, 0x07060302u);
}
static __device__ __forceinline__ bf16x8 pack8(float4 v0, float4 v1){
    union { bf16x8 v; unsigned int d[4]; } r;
    r.d[0] = pack2(v0.x, v0.y);
    r.d[1] = pack2(v0.z, v0.w);
    r.d[2] = pack2(v1.x, v1.y);
    r.d[3] = pack2(v1.z, v1.w);
    return r.v;
}
static __device__ __forceinline__ float b2f(unsigned short h){
    union { unsigned int u; float f; } x; x.u = ((unsigned int)h) << 16; return x.f;
}
// fp16 pack/unpack for edge weights (w in [0,1): rel err 2^-11)
static __device__ __forceinline__ unsigned short f2h(float f){
    union { _Float16 h; unsigned short u; } x; x.h = (_Float16)f; return x.u;
}
static __device__ __forceinline__ float h2f(unsigned short u){
    union { unsigned short u; _Float16 h; } x; x.u = u; return (float)x.h;
}

// sense-reversing grid barrier: bar[0]=arrival count, bar[1]=generation.
// Agent-scope acq_rel arrival flushes this XCD's L2 (release); waiters'
// acquire loads invalidate -> cross-XCD visibility of all prior stores.
static __device__ __forceinline__ void gbar(int* __restrict__ bar){
    __syncthreads();
    if (threadIdx.x == 0){
        int g = __hip_atomic_load(&bar[1], __ATOMIC_RELAXED, __HIP_MEMORY_SCOPE_AGENT);
        int old = __hip_atomic_fetch_add(&bar[0], 1, __ATOMIC_ACQ_REL, __HIP_MEMORY_SCOPE_AGENT);
        if (old == GRID-1){
            __hip_atomic_store(&bar[0], 0, __ATOMIC_RELAXED, __HIP_MEMORY_SCOPE_AGENT);
            __hip_atomic_store(&bar[1], g+1, __ATOMIC_RELEASE, __HIP_MEMORY_SCOPE_AGENT);
        } else {
            int cur, tries = 0;
            do {
                __builtin_amdgcn_s_sleep(2);
                cur = __hip_atomic_load(&bar[1], __ATOMIC_ACQUIRE, __HIP_MEMORY_SCOPE_AGENT);
            } while (cur == g && ++tries < SPIN_CAP);
        }
    }
    __syncthreads();
}

__global__ void init_bar(int* __restrict__ bar, int* __restrict__ gflag){
    int t = threadIdx.x;
    if (t < 2)  bar[t] = 0;
    if (t < 64) gflag[t] = 0;
}

__global__ __launch_bounds__(256, 4) void mega(
    const float* __restrict__ X,
    const float* __restrict__ W1, const float* __restrict__ W2,
    const float* __restrict__ b1, const float* __restrict__ b2,
    const int* __restrict__ esrc, const int* __restrict__ edst,
    const float* __restrict__ ew,
    unsigned short* __restrict__ W1t, unsigned short* __restrict__ W2t,
    unsigned short* __restrict__ S1, unsigned short* __restrict__ H,
    unsigned short* __restrict__ S2,
    int* __restrict__ offs, int* __restrict__ cnt8, int* __restrict__ sbase,
    unsigned short* __restrict__ slot, unsigned int* __restrict__ edges,
    int* __restrict__ gflag, int* __restrict__ bar, float* __restrict__ out,
    int N, int E, int gemm_nt, int nb)
{
    __shared__ unsigned short sB[128*136];  // gemm1 B-tile; reused as [48][136] in gemm2
    __shared__ int sd[256];
    __shared__ int s_excl;

    int tid = threadIdx.x, bid = blockIdx.x;
    int gid = bid*256 + tid;
    int wave = tid >> 6, lane = tid & 63;
    int quad = lane >> 4, l16 = lane & 15;

    // ---------------- P0: prep (cnt8 zero, W transposes) ----------------
    {
        int n8_4 = N*2;   // N*8 ints as int4
        for (int i = gid; i < n8_4; i += GSZ) ((int4*)cnt8)[i] = (int4){0,0,0,0};
        for (int i = gid; i < F0*F1; i += GSZ){       // W1 [512][128] -> W1t [128][512]
            int k = i >> 7, n = i & 127;
            W1t[n*F0 + k] = f2b(W1[i]);
        }
        if (gid < F2P*F1){                            // W2 [128][40] -> W2t [48][128]
            int n = gid >> 7, k = gid & 127;
            float v = (n < F2) ? W2[(size_t)k*F2 + n] : 0.f;
            W2t[gid] = f2b(v);
        }
    }
    gbar(bar);

    // ---------------- P1: gemm1 tiles (grid-stride) + hist ----------------
    for (int t = bid; t < gemm_nt; t += GRID){
        int row0 = t * 64;
        int arow = min(row0 + wave*16 + l16, N-1);
        const float* xrow = X + (size_t)arow * F0;
        f32x4 acc[8];
        #pragma unroll
        for (int c=0;c<8;c++) acc[c] = (f32x4){0.f,0.f,0.f,0.f};

        #pragma unroll 1
        for (int p = 0; p < 4; p++){
            __syncthreads();   // prior phase's LDS reads done
            // A loads for this phase: 8 independent float4, land under staging
            const float* xr = xrow + p*128 + quad*8;
            float4 v0 = *(const float4*)(xr +  0), v1 = *(const float4*)(xr +  4);
            float4 v2 = *(const float4*)(xr + 32), v3 = *(const float4*)(xr + 36);
            float4 v4 = *(const float4*)(xr + 64), v5 = *(const float4*)(xr + 68);
            float4 v6 = *(const float4*)(xr + 96), v7 = *(const float4*)(xr + 100);
            // stage B phase p: 2048 float4s across 256 threads
            #pragma unroll
            for (int i=0;i<8;i++){
                int idx = tid + i*256;
                int nn = idx >> 4, c8 = idx & 15;
                *(float4*)&sB[nn*136 + c8*8] =
                    *(const float4*)&W1t[(size_t)nn*F0 + p*128 + c8*8];
            }
            __syncthreads();
            bf16x8 a0 = pack8(v0, v1), a1 = pack8(v2, v3);
            bf16x8 a2 = pack8(v4, v5), a3 = pack8(v6, v7);
            #pragma unroll
            for (int c=0;c<8;c++){
                bf16x8 b0 = *(bf16x8*)&sB[(c*16 + l16)*136 + 0*32 + quad*8];
                acc[c] = __builtin_amdgcn_mfma_f32_16x16x32_bf16(a0, b0, acc[c], 0, 0, 0);
                bf16x8 b1 = *(bf16x8*)&sB[(c*16 + l16)*136 + 1*32 + quad*8];
                acc[c] = __builtin_amdgcn_mfma_f32_16x16x32_bf16(a1, b1, acc[c], 0, 0, 0);
                bf16x8 b2 = *(bf16x8*)&sB[(c*16 + l16)*136 + 2*32 + quad*8];
                acc[c] = __builtin_amdgcn_mfma_f32_16x16x32_bf16(a2, b2, acc[c], 0, 0, 0);
                bf16x8 b3 = *(bf16x8*)&sB[(c*16 + l16)*136 + 3*32 + quad*8];
                acc[c] = __builtin_amdgcn_mfma_f32_16x16x32_bf16(a3, b3, acc[c], 0, 0, 0);
            }
        }
        // C/D: col = c*16 + l16, row = quad*4 + r
        #pragma unroll
        for (int c=0;c<8;c++){
            #pragma unroll
            for (int r=0;r<4;r++){
                int grow = row0 + wave*16 + quad*4 + r;
                if (grow < N) S1[(size_t)grow*F1 + c*16 + l16] = f2b_fast(acc[c][r]);
            }
        }
    }
    // hist: 8-way sharded histogram (idle blocks start here immediately)
    for (int e = gid; e < E; e += GSZ){
        int d = edst[e];
        slot[e] = (unsigned short)atomicAdd(&cnt8[d*8 + (e & 7)], 1);
    }
    gbar(bar);

    // ---------------- P2: scan (blocks 0..nb-1, flag-spin lookback) ----------------
    if (bid < nb){
        int base = bid*1024 + tid*4;
        int t4[4];
        int lpr[4][8];
        #pragma unroll
        for (int j=0;j<4;j++){
            int node = base+j;
            int tot = 0;
            #pragma unroll
            for (int k=0;k<8;k++) lpr[j][k] = 0;
            if (node < N){
                int4 c0 = *(const int4*)&cnt8[(size_t)node*8];
                int4 c1 = *(const int4*)&cnt8[(size_t)node*8+4];
                int run;
                lpr[j][0] = 0;   run  = c0.x;
                lpr[j][1] = run; run += c0.y;
                lpr[j][2] = run; run += c0.z;
                lpr[j][3] = run; run += c0.w;
                lpr[j][4] = run; run += c1.x;
                lpr[j][5] = run; run += c1.y;
                lpr[j][6] = run; run += c1.z;
                lpr[j][7] = run; run += c1.w;
                tot = run;
            }
            t4[j] = tot;
        }
        int v1 = t4[0], v2 = t4[0]+t4[1], v3 = v2+t4[2];
        int s = v3 + t4[3];
        sd[tid] = s; __syncthreads();
        for (int off=1; off<256; off<<=1){
            int tt = (tid>=off) ? sd[tid-off] : 0;
            __syncthreads();
            sd[tid] += tt;
            __syncthreads();
        }
        int excl = sd[tid] - s;
        int btot = sd[255];

        if (tid == 0)
            __hip_atomic_store(&gflag[bid], btot + 1, __ATOMIC_RELEASE, __HIP_MEMORY_SCOPE_AGENT);
        if (tid < 64){
            int v = 0;
            if (tid < bid){
                int g, tries = 0;
                do {
                    g = __hip_atomic_load(&gflag[tid], __ATOMIC_ACQUIRE, __HIP_MEMORY_SCOPE_AGENT);
                    if (g == 0) __builtin_amdgcn_s_sleep(1);
                } while (g == 0 && ++tries < SPIN_CAP);
                v = g - 1;
            }
            #pragma unroll
            for (int o=1; o<64; o<<=1) v += __shfl_xor(v, o);
            if (tid == 0) s_excl = v;
        }
        __syncthreads();

        int node_off[4] = {0, v1, v2, v3};
        int gexcl = s_excl + excl;
        #pragma unroll
        for (int j=0;j<4;j++){
            int node = base+j;
            if (node < N){
                int o = gexcl + node_off[j];
                offs[node] = o;
                int4 s0, s1;
                s0.x = o + lpr[j][0]; s0.y = o + lpr[j][1];
                s0.z = o + lpr[j][2]; s0.w = o + lpr[j][3];
                s1.x = o + lpr[j][4]; s1.y = o + lpr[j][5];
                s1.z = o + lpr[j][6]; s1.w = o + lpr[j][7];
                *(int4*)&sbase[(size_t)node*8]   = s0;
                *(int4*)&sbase[(size_t)node*8+4] = s1;
            }
        }
        if (bid == 0 && tid == 0) offs[N] = E;
    }
    gbar(bar);

    // ---------------- P3: scatter (atomic-free; pos clamped for safety) ----------------
    for (int e = gid; e < E; e += GSZ){
        int d = edst[e];
        int pos = sbase[d*8 + (e & 7)] + (int)slot[e];
        pos = min(max(pos, 0), E-1);
        edges[pos] = ((unsigned int)esrc[e] << 16) | (unsigned int)f2h(ew[e]);
    }
    gbar(bar);

    // ---------------- P4: agg1  H = relu(A@S1 + b1) ----------------
    {
        int half = lane >> 5, fl = lane & 31;
        for (int node = bid*4 + wave; node < N; node += GRID*4){
            int e0 = offs[node], e1 = offs[node+1];
            double a0=0.0, a1=0.0, a2=0.0, a3=0.0;
            int e = e0;
            for (; e+8 <= e1; e += 8){
                unsigned int rA = edges[e   + half];
                unsigned int rB = edges[e+2 + half];
                unsigned int rC = edges[e+4 + half];
                unsigned int rD = edges[e+6 + half];
                ushort4 vA = *(const ushort4*)&S1[((size_t)(rA>>16))*F1 + fl*4];
                ushort4 vB = *(const ushort4*)&S1[((size_t)(rB>>16))*F1 + fl*4];
                ushort4 vC = *(const ushort4*)&S1[((size_t)(rC>>16))*F1 + fl*4];
                ushort4 vD = *(const ushort4*)&S1[((size_t)(rD>>16))*F1 + fl*4];
                double wA = h2f((unsigned short)rA), wB = h2f((unsigned short)rB);
                double wC = h2f((unsigned short)rC), wD = h2f((unsigned short)rD);
                a0 += wA*b2f(vA.x) + wB*b2f(vB.x) + wC*b2f(vC.x) + wD*b2f(vD.x);
                a1 += wA*b2f(vA.y) + wB*b2f(vB.y) + wC*b2f(vC.y) + wD*b2f(vD.y);
                a2 += wA*b2f(vA.z) + wB*b2f(vB.z) + wC*b2f(vC.z) + wD*b2f(vD.z);
                a3 += wA*b2f(vA.w) + wB*b2f(vB.w) + wC*b2f(vC.w) + wD*b2f(vD.w);
            }
            for (; e < e1; e += 2){
                int ee = e + half;
                if (ee < e1){
                    unsigned int r = edges[ee];
                    ushort4 v = *(const ushort4*)&S1[((size_t)(r>>16))*F1 + fl*4];
                    double w = h2f((unsigned short)r);
                    a0 += w*b2f(v.x); a1 += w*b2f(v.y); a2 += w*b2f(v.z); a3 += w*b2f(v.w);
                }
            }
            a0 += __shfl_down(a0, 32);
            a1 += __shfl_down(a1, 32);
            a2 += __shfl_down(a2, 32);
            a3 += __shfl_down(a3, 32);
            if (lane < 32){
                float4 bb = *(const float4*)&b1[fl*4];
                float o0 = (float)(a0 + (double)bb.x);
                float o1 = (float)(a1 + (double)bb.y);
                float o2 = (float)(a2 + (double)bb.z);
                float o3 = (float)(a3 + (double)bb.w);
                o0 = o0>0.f?o0:0.f; o1 = o1>0.f?o1:0.f;
                o2 = o2>0.f?o2:0.f; o3 = o3>0.f?o3:0.f;
                union { ushort4 v; unsigned int d[2]; } o;
                o.d[0] = pack2(o0, o1);
                o.d[1] = pack2(o2, o3);
                *(ushort4*)&H[(size_t)node*F1 + fl*4] = o.v;
            }
        }
    }
    gbar(bar);

    // ---------------- P5: gemm2  S2 = H @ W2t ----------------
    {
        unsigned short (*sB2)[136] = (unsigned short(*)[136])sB;
        for (int i = tid; i < 48*16; i += 256){
            int nn = i >> 4, p = i & 15;
            *(float4*)&sB2[nn][p*8] = *(const float4*)&W2t[(size_t)nn*F1 + p*8];
        }
        __syncthreads();
        for (int t = bid; t < gemm_nt; t += GRID){
            int row0 = t * 64;
            int arow = min(row0 + wave*16 + l16, N-1);
            const unsigned short* hrow = H + (size_t)arow * F1;
            bf16x8 a[4];
            #pragma unroll
            for (int ks=0; ks<4; ks++) a[ks] = *(const bf16x8*)(hrow + ks*32 + quad*8);
            f32x4 acc[3];
            #pragma unroll
            for (int c=0;c<3;c++) acc[c] = (f32x4){0.f,0.f,0.f,0.f};
            #pragma unroll
            for (int ks=0; ks<4; ks++){
                #pragma unroll
                for (int c=0;c<3;c++){
                    bf16x8 b = *(bf16x8*)&sB2[c*16 + l16][ks*32 + quad*8];
                    acc[c] = __builtin_amdgcn_mfma_f32_16x16x32_bf16(a[ks], b, acc[c], 0, 0, 0);
                }
            }
            #pragma unroll
            for (int c=0;c<3;c++){
                #pragma unroll
                for (int r=0;r<4;r++){
                    int grow = row0 + wave*16 + quad*4 + r;
                    if (grow < N) S2[(size_t)grow*F2P + c*16 + l16] = f2b_fast(acc[c][r]);
                }
            }
        }
    }
    gbar(bar);

    // ---------------- P6: agg2  out = A@S2 + b2 ----------------
    {
        int grp = lane >> 4, gl = lane & 15;
        bool act = gl < 10;
        for (int node = bid*4 + wave; node < N; node += GRID*4){
            int e0 = offs[node], e1 = offs[node+1];
            double a0=0.0, a1=0.0, a2=0.0, a3=0.0;
            for (int e = e0; e < e1; e += 4){
                int ee = e + grp;
                if (ee < e1 && act){
                    unsigned int r = edges[ee];
                    ushort4 v = *(const ushort4*)&S2[((size_t)(r>>16))*F2P + gl*4];
                    double w = h2f((unsigned short)r);
                    a0 += w*b2f(v.x); a1 += w*b2f(v.y); a2 += w*b2f(v.z); a3 += w*b2f(v.w);
                }
            }
            a0 += __shfl_down(a0, 32); a0 += __shfl_down(a0, 16);
            a1 += __shfl_down(a1, 32); a1 += __shfl_down(a1, 16);
            a2 += __shfl_down(a2, 32); a2 += __shfl_down(a2, 16);
            a3 += __shfl_down(a3, 32); a3 += __shfl_down(a3, 16);
            if (lane < 10){
                float4 bb = *(const float4*)&b2[lane*4];
                float4 o;
                o.x = (float)(a0 + (double)bb.x);
                o.y = (float)(a1 + (double)bb.y);
                o.z = (float)(a2 + (double)bb.z);
                o.w = (float)(a3 + (double)bb.w);
                *(float4*)&out[(size_t)node*F2 + lane*4] = o;
            }
        }
    }
}

extern "C" void kernel_launch(void* const* d_in, const int* in_sizes, int n_in,
                              void* d_out, int out_size, void* d_ws, size_t ws_size,
                              hipStream_t stream){
    const float* x    = (const float*)d_in[0];
    const int*   esrc = (const int*)d_in[1];
    const int*   edst = (const int*)d_in[2];
    const float* ew   = (const float*)d_in[3];
    const float* W1   = (const float*)d_in[4];
    const float* b1   = (const float*)d_in[5];
    const float* W2   = (const float*)d_in[6];
    const float* b2   = (const float*)d_in[7];
    float* out = (float*)d_out;
    int N = in_sizes[0] / F0;   // 50000
    int E = in_sizes[1];        // 800000

    char* ws = (char*)d_ws;
    size_t off = 0;
    auto alloc = [&](size_t bytes)->void*{
        void* p = ws + off; off += (bytes + 255) & ~(size_t)255; return p;
    };
    unsigned short* S1 = (unsigned short*)alloc(sizeof(unsigned short)*(size_t)N*F1);  // 12.8 MB
    unsigned short* H  = (unsigned short*)alloc(sizeof(unsigned short)*(size_t)N*F1);  // 12.8 MB
    unsigned short* S2 = (unsigned short*)alloc(sizeof(unsigned short)*(size_t)N*F2P); // 4.8 MB
    unsigned short* W1t = (unsigned short*)alloc(sizeof(unsigned short)*F1*F0);
    unsigned short* W2t = (unsigned short*)alloc(sizeof(unsigned short)*F2P*F1);
    int*   offs  = (int*)alloc(sizeof(int)*(size_t)(N+1));
    int*   cnt8  = (int*)alloc(sizeof(int)*(size_t)N*8);                 // 1.6 MB
    int*   sbase = (int*)alloc(sizeof(int)*(size_t)N*8);                 // 1.6 MB
    unsigned short* slot = (unsigned short*)alloc(sizeof(unsigned short)*(size_t)E);   // 1.6 MB
    unsigned int* edges = (unsigned int*)alloc(sizeof(unsigned int)*(size_t)E);        // 3.2 MB
    int*   gflag = (int*)alloc(sizeof(int)*64);
    int*   bar   = (int*)alloc(sizeof(int)*64);

    int gemm_nt = (N+63)/64;      // 782
    int nb = (N+1023)/1024;       // 49 <= 64 (scan lookback assumes this)

    init_bar<<<1,64,0,stream>>>(bar, gflag);
    mega<<<GRID,256,0,stream>>>(x, W1, W2, b1, b2, esrc, edst, ew,
                                W1t, W2t, S1, H, S2,
                                offs, cnt8, sbase, slot, edges,
                                gflag, bar, out, N, E, gemm_nt, nb);
}

// Round 7
// 311.499 us; speedup vs baseline: 4.1579x; 4.1579x over previous
//
#include <hip/hip_runtime.h>

// GCN 2-layer forward on MI355X (gfx950).
// out = A @ relu(A @ (x@W1) + b1) @ W2 + b2   (A = weighted edge aggregation)
// R14: back to the 7-dispatch R9 pipeline + spill-free gemm1.
//  - R13 megakernel verdict: grid barrier on one cacheline ~130us/barrier;
//    and aggregate HBM shows the WORK is ~280-300us, dispatch gaps ~5us each.
//    Fusion is not the lever; per-phase efficiency is.
//  - hipcc pins this kernel family at ~56-68 VGPR and spills anything held
//    across the B-staging loop (R9/R10/R13 evidence). New gemm1 inner loop
//    holds only acc(32)+2 float4(8)+frag(4): load-pack-mfma per k-step.
//    Zero spill expected => gemm1h WRITE_SIZE 39MB -> ~16.5MB (signature).
//  - scan_fused / scatter / aggs / gemm2 verbatim from R9 (303us best).

#define F0 512
#define F1 128
#define F2 40
#define F2P 48   // padded S2 row (bf16)

typedef short bf16x8 __attribute__((ext_vector_type(8)));
typedef float f32x4 __attribute__((ext_vector_type(4)));

// accurate RNE bf16 (weights, once per call)
static __device__ __forceinline__ unsigned short f2b(float f){
    union { float f; unsigned int u; } x; x.f = f;
    unsigned int u = x.u;
    unsigned int r = (u + 0x7fffu + ((u >> 16) & 1u)) >> 16;
    return (unsigned short)r;
}
// fast round-half-up bf16 (activations)
static __device__ __forceinline__ unsigned short f2b_fast(float f){
    return (unsigned short)((__float_as_uint(f) + 0x8000u) >> 16);
}
static __device__ __forceinline__ unsigned int pack2(float a, float b){
    unsigned int ua = __float_as_uint(a) + 0x8000u;
    unsigned int ub = __float_as_uint(b) + 0x8000u;
    return __builtin_amdgcn_perm(ub, ua, 0x07060302u);
}
static __device__ __forceinline__ bf16x8 pack8(float4 v0, float4 v1){
    union { bf16x8 v; unsigned int d[4]; } r;
    r.d[0] = pack2(v0.x, v0.y);
    r.d[1] = pack2(v0.z, v0.w);
    r.d[2] = pack2(v1.x, v1.y);
    r.d[3] = pack2(v1.z, v1.w);
    return r.v;
}
static __device__ __forceinline__ float b2f(unsigned short h){
    union { unsigned int u; float f; } x; x.u = ((unsigned int)h) << 16; return x.f;
}
// fp16 pack/unpack for edge weights (w in [0,1): rel err 2^-11)
static __device__ __forceinline__ unsigned short f2h(float f){
    union { _Float16 h; unsigned short u; } x; x.h = (_Float16)f; return x.u;
}
static __device__ __forceinline__ float h2f(unsigned short u){
    union { unsigned short u; _Float16 h; } x; x.u = u; return (float)x.h;
}

// ---------------- weight prep + cnt8/gflag zero (fused) ----------------
__global__ void prep_w(const float* __restrict__ W1, const float* __restrict__ W2,
                       unsigned short* __restrict__ W1t, unsigned short* __restrict__ W2t,
                       int* __restrict__ cnt8, int n8, int* __restrict__ gflag){
    int idx = blockIdx.x*256 + threadIdx.x;   // grid covers max(400000, 71680)
    if (idx < n8) cnt8[idx] = 0;
    if (idx < 64) gflag[idx] = 0;             // scan cross-block flags
    if (idx < F0*F1){                    // W1 [512][128] -> W1t [128][512]
        int k = idx >> 7, n = idx & 127;
        W1t[(size_t)n*F0 + k] = f2b(W1[idx]);
    } else if (idx < F0*F1 + F2P*F1){    // W2 [128][40] -> W2t [48][128]
        int j = idx - F0*F1;
        int n = j >> 7, k = j & 127;
        float v = (n < F2) ? W2[(size_t)k*F2 + n] : 0.f;
        W2t[j] = f2b(v);
    }
}

// ---- GEMM1 + hist tail: X[M,512]fp32 @ W1t -> S1 bf16 [M,128] ----
// Minimal-register inner loop: per k-step load 2xfloat4 X, pack8, 8 MFMAs.
// Live set ~56 VGPR (acc 32 + v 8 + frag 4 + addr) -- fits hipcc's observed
// 56-68 budget with no scratch. Bit-identical rounding to R9.
__global__ __launch_bounds__(256, 3) void gemm1h(const float* __restrict__ X,
                                                 const unsigned short* __restrict__ W1t,
                                                 unsigned short* __restrict__ S1, int M,
                                                 const int* __restrict__ dst,
                                                 int* __restrict__ cnt8,
                                                 unsigned short* __restrict__ slot,
                                                 int E, int epb){
    __shared__ unsigned short sB[128*136];  // [n][136]: 272B stride -> 2-way alias (free)
    int tid = threadIdx.x;
    int wave = tid >> 6, lane = tid & 63;
    int quad = lane >> 4, l16 = lane & 15;
    int row0 = blockIdx.x * 64;
    int arow = min(row0 + wave*16 + l16, M-1);
    const float* xrow = X + (size_t)arow * F0;

    f32x4 acc[8];
    #pragma unroll
    for (int c=0;c<8;c++) acc[c] = (f32x4){0.f,0.f,0.f,0.f};

    #pragma unroll 1
    for (int p = 0; p < 4; p++){
        __syncthreads();   // prior phase's LDS reads done
        // stage B phase p: 2048 float4s across 256 threads (8 iters)
        #pragma unroll
        for (int i=0;i<8;i++){
            int idx = tid + i*256;          // 0..2047
            int nn = idx >> 4, c8 = idx & 15;
            *(float4*)&sB[nn*136 + c8*8] =
                *(const float4*)&W1t[(size_t)nn*F0 + p*128 + c8*8];
        }
        __syncthreads();
        #pragma unroll
        for (int s=0;s<4;s++){
            const float* xr = xrow + p*128 + s*32 + quad*8;
            float4 v0 = *(const float4*)(xr);
            float4 v1 = *(const float4*)(xr + 4);
            bf16x8 af = pack8(v0, v1);
            #pragma unroll
            for (int c=0;c<8;c++){
                bf16x8 b = *(bf16x8*)&sB[(c*16 + l16)*136 + s*32 + quad*8];
                acc[c] = __builtin_amdgcn_mfma_f32_16x16x32_bf16(af, b, acc[c], 0, 0, 0);
            }
        }
    }
    // C/D: col = c*16 + l16, row = quad*4 + r
    #pragma unroll
    for (int c=0;c<8;c++){
        #pragma unroll
        for (int r=0;r<4;r++){
            int grow = row0 + wave*16 + quad*4 + r;
            if (grow < M) S1[(size_t)grow*F1 + c*16 + l16] = f2b_fast(acc[c][r]);
        }
    }

    // ---- hist tail: this block's edge slice (no barrier needed) ----
    int ebase = blockIdx.x * epb;
    int eend  = min(ebase + epb, E);
    for (int e = ebase + tid; e < eend; e += 256){
        int d = dst[e];
        int s = e & 7;                       // shard by low edge bits
        slot[e] = (unsigned short)atomicAdd(&cnt8[d*8 + s], 1);
    }
}

// ---------------- fused scan: per-chunk scan + cross-block prefix ----------------
// 49 blocks (1024 nodes each), all co-resident -> flag-spin is deadlock-free.
__global__ void scan_fused(const int* __restrict__ cnt8, int* __restrict__ offs,
                           int* __restrict__ sbase, int* __restrict__ gflag,
                           int n, int E){
    __shared__ int sd[256];
    __shared__ int s_excl;
    int tid = threadIdx.x, bid = blockIdx.x;
    int base = bid*1024 + tid*4;

    int t[4];
    int lpr[4][8];
    #pragma unroll
    for (int j=0;j<4;j++){
        int node = base+j;
        int tot = 0;
        #pragma unroll
        for (int k=0;k<8;k++) lpr[j][k] = 0;
        if (node < n){
            int4 c0 = *(const int4*)&cnt8[(size_t)node*8];
            int4 c1 = *(const int4*)&cnt8[(size_t)node*8+4];
            int run;
            lpr[j][0] = 0;   run  = c0.x;
            lpr[j][1] = run; run += c0.y;
            lpr[j][2] = run; run += c0.z;
            lpr[j][3] = run; run += c0.w;
            lpr[j][4] = run; run += c1.x;
            lpr[j][5] = run; run += c1.y;
            lpr[j][6] = run; run += c1.z;
            lpr[j][7] = run; run += c1.w;
            tot = run;
        }
        t[j] = tot;
    }
    int v1 = t[0], v2 = t[0]+t[1], v3 = v2+t[2];
    int s = v3 + t[3];
    sd[tid] = s; __syncthreads();
    for (int off=1; off<256; off<<=1){
        int tt = (tid>=off) ? sd[tid-off] : 0;
        __syncthreads();
        sd[tid] += tt;
        __syncthreads();
    }
    int excl = sd[tid] - s;
    int btot = sd[255];

    // publish this block's total (value+1 so 0 == not-ready)
    if (tid == 0)
        __hip_atomic_store(&gflag[bid], btot + 1, __ATOMIC_RELEASE, __HIP_MEMORY_SCOPE_AGENT);
    // wave 0: gather predecessors' totals (bid <= 48 < 64 lanes)
    if (tid < 64){
        int v = 0;
        if (tid < bid){
            int g;
            do {
                g = __hip_atomic_load(&gflag[tid], __ATOMIC_ACQUIRE, __HIP_MEMORY_SCOPE_AGENT);
                if (g == 0) __builtin_amdgcn_s_sleep(1);
            } while (g == 0);
            v = g - 1;
        }
        #pragma unroll
        for (int o=1; o<64; o<<=1) v += __shfl_xor(v, o);
        if (tid == 0) s_excl = v;
    }
    __syncthreads();

    int node_off[4] = {0, v1, v2, v3};
    int gexcl = s_excl + excl;
    #pragma unroll
    for (int j=0;j<4;j++){
        int node = base+j;
        if (node < n){
            int o = gexcl + node_off[j];
            offs[node] = o;
            int4 s0, s1;
            s0.x = o + lpr[j][0]; s0.y = o + lpr[j][1];
            s0.z = o + lpr[j][2]; s0.w = o + lpr[j][3];
            s1.x = o + lpr[j][4]; s1.y = o + lpr[j][5];
            s1.z = o + lpr[j][6]; s1.w = o + lpr[j][7];
            *(int4*)&sbase[(size_t)node*8]   = s0;
            *(int4*)&sbase[(size_t)node*8+4] = s1;
        }
    }
    if (bid == 0 && tid == 0) offs[n] = E;
}

// atomic-free scatter: pos = sbase[d][shard] + saved slot
__global__ void scatter_kernel(const int* __restrict__ src, const int* __restrict__ dst,
                               const float* __restrict__ w,
                               const int* __restrict__ sbase,
                               const unsigned short* __restrict__ slot,
                               unsigned int* __restrict__ edges, int E){
    int e = blockIdx.x*256+threadIdx.x;
    if (e<E){
        int d = dst[e];
        int pos = sbase[d*8 + (e & 7)] + (int)slot[e];
        edges[pos] = ((unsigned int)src[e] << 16) | (unsigned int)f2h(w[e]);
    }
}

// ---- agg1: H = relu(A@S1 + b1) bf16, F=128 (unchanged) ----
__global__ void agg1_kernel(const unsigned short* __restrict__ S1, const int* __restrict__ offs,
                            const unsigned int* __restrict__ edges,
                            const float* __restrict__ b1, unsigned short* __restrict__ H, int n){
    int node = blockIdx.x*4 + (threadIdx.x >> 6);   // one wave per node
    int lane = threadIdx.x & 63;
    if (node >= n) return;
    int half = lane >> 5, fl = lane & 31;
    int e0 = offs[node], e1 = offs[node+1];
    double a0=0.0, a1=0.0, a2=0.0, a3=0.0;
    int e = e0;
    for (; e+8 <= e1; e += 8){
        unsigned int rA = edges[e   + half];
        unsigned int rB = edges[e+2 + half];
        unsigned int rC = edges[e+4 + half];
        unsigned int rD = edges[e+6 + half];
        ushort4 vA = *(const ushort4*)&S1[((size_t)(rA>>16))*F1 + fl*4];
        ushort4 vB = *(const ushort4*)&S1[((size_t)(rB>>16))*F1 + fl*4];
        ushort4 vC = *(const ushort4*)&S1[((size_t)(rC>>16))*F1 + fl*4];
        ushort4 vD = *(const ushort4*)&S1[((size_t)(rD>>16))*F1 + fl*4];
        double wA = h2f((unsigned short)rA), wB = h2f((unsigned short)rB);
        double wC = h2f((unsigned short)rC), wD = h2f((unsigned short)rD);
        a0 += wA*b2f(vA.x) + wB*b2f(vB.x) + wC*b2f(vC.x) + wD*b2f(vD.x);
        a1 += wA*b2f(vA.y) + wB*b2f(vB.y) + wC*b2f(vC.y) + wD*b2f(vD.y);
        a2 += wA*b2f(vA.z) + wB*b2f(vB.z) + wC*b2f(vC.z) + wD*b2f(vD.z);
        a3 += wA*b2f(vA.w) + wB*b2f(vB.w) + wC*b2f(vC.w) + wD*b2f(vD.w);
    }
    for (; e < e1; e += 2){
        int ee = e + half;
        if (ee < e1){
            unsigned int r = edges[ee];
            ushort4 v = *(const ushort4*)&S1[((size_t)(r>>16))*F1 + fl*4];
            double w = h2f((unsigned short)r);
            a0 += w*b2f(v.x); a1 += w*b2f(v.y); a2 += w*b2f(v.z); a3 += w*b2f(v.w);
        }
    }
    a0 += __shfl_down(a0, 32);
    a1 += __shfl_down(a1, 32);
    a2 += __shfl_down(a2, 32);
    a3 += __shfl_down(a3, 32);
    if (lane < 32){
        float4 bb = *(const float4*)&b1[fl*4];
        float o0 = (float)(a0 + (double)bb.x);
        float o1 = (float)(a1 + (double)bb.y);
        float o2 = (float)(a2 + (double)bb.z);
        float o3 = (float)(a3 + (double)bb.w);
        o0 = o0>0.f?o0:0.f; o1 = o1>0.f?o1:0.f;
        o2 = o2>0.f?o2:0.f; o3 = o3>0.f?o3:0.f;
        union { ushort4 v; unsigned int d[2]; } o;
        o.d[0] = pack2(o0, o1);
        o.d[1] = pack2(o2, o3);
        *(ushort4*)&H[(size_t)node*F1 + fl*4] = o.v;
    }
}

// ---- GEMM2: H bf16 [M,128] @ W2t -> S2 bf16 [M,48] (unchanged) ----
__global__ __launch_bounds__(256) void gemm2_mfma(const unsigned short* __restrict__ H,
                                                  const unsigned short* __restrict__ W2t,
                                                  unsigned short* __restrict__ S2, int M){
    __shared__ unsigned short sB[48][136];
    int tid = threadIdx.x;
    int wave = tid >> 6, lane = tid & 63;
    int quad = lane >> 4, l16 = lane & 15;
    for (int i = tid; i < 48*16; i += 256){
        int nn = i >> 4, p = i & 15;
        *(float4*)&sB[nn][p*8] = *(const float4*)&W2t[(size_t)nn*F1 + p*8];
    }
    int row0 = blockIdx.x * 64;
    int myrow = row0 + wave*16 + l16;
    int arow = min(myrow, M-1);
    const unsigned short* hrow = H + (size_t)arow * F1;
    bf16x8 a[4];
    #pragma unroll
    for (int ks=0; ks<4; ks++) a[ks] = *(const bf16x8*)(hrow + ks*32 + quad*8);
    __syncthreads();
    f32x4 acc[3];
    #pragma unroll
    for (int c=0;c<3;c++) acc[c] = (f32x4){0.f,0.f,0.f,0.f};
    #pragma unroll
    for (int ks=0; ks<4; ks++){
        #pragma unroll
        for (int c=0;c<3;c++){
            bf16x8 b = *(bf16x8*)&sB[c*16 + l16][ks*32 + quad*8];
            acc[c] = __builtin_amdgcn_mfma_f32_16x16x32_bf16(a[ks], b, acc[c], 0, 0, 0);
        }
    }
    #pragma unroll
    for (int c=0;c<3;c++){
        #pragma unroll
        for (int r=0;r<4;r++){
            int grow = row0 + wave*16 + quad*4 + r;
            if (grow < M) S2[(size_t)grow*F2P + c*16 + l16] = f2b_fast(acc[c][r]);
        }
    }
}

// ---- agg2: out = A@S2 + b2, F=40 (unchanged) ----
__global__ void agg2_kernel(const unsigned short* __restrict__ S2, const int* __restrict__ offs,
                            const unsigned int* __restrict__ edges,
                            const float* __restrict__ b2, float* __restrict__ out, int n){
    int node = blockIdx.x*4 + (threadIdx.x >> 6);  // one wave per node
    int lane = threadIdx.x & 63;
    if (node >= n) return;
    int grp = lane >> 4, gl = lane & 15;
    bool act = gl < 10;
    int e0 = offs[node], e1 = offs[node+1];
    double a0=0.0, a1=0.0, a2=0.0, a3=0.0;
    for (int e = e0; e < e1; e += 4){
        int ee = e + grp;
        if (ee < e1 && act){
            unsigned int r = edges[ee];
            ushort4 v = *(const ushort4*)&S2[((size_t)(r>>16))*F2P + gl*4];
            double w = h2f((unsigned short)r);
            a0 += w*b2f(v.x); a1 += w*b2f(v.y); a2 += w*b2f(v.z); a3 += w*b2f(v.w);
        }
    }
    a0 += __shfl_down(a0, 32); a0 += __shfl_down(a0, 16);
    a1 += __shfl_down(a1, 32); a1 += __shfl_down(a1, 16);
    a2 += __shfl_down(a2, 32); a2 += __shfl_down(a2, 16);
    a3 += __shfl_down(a3, 32); a3 += __shfl_down(a3, 16);
    if (lane < 10){
        float4 bb = *(const float4*)&b2[lane*4];
        float4 o;
        o.x = (float)(a0 + (double)bb.x);
        o.y = (float)(a1 + (double)bb.y);
        o.z = (float)(a2 + (double)bb.z);
        o.w = (float)(a3 + (double)bb.w);
        *(float4*)&out[(size_t)node*F2 + lane*4] = o;
    }
}

extern "C" void kernel_launch(void* const* d_in, const int* in_sizes, int n_in,
                              void* d_out, int out_size, void* d_ws, size_t ws_size,
                              hipStream_t stream){
    const float* x    = (const float*)d_in[0];
    const int*   esrc = (const int*)d_in[1];
    const int*   edst = (const int*)d_in[2];
    const float* ew   = (const float*)d_in[3];
    const float* W1   = (const float*)d_in[4];
    const float* b1   = (const float*)d_in[5];
    const float* W2   = (const float*)d_in[6];
    const float* b2   = (const float*)d_in[7];
    float* out = (float*)d_out;
    int N = in_sizes[0] / F0;   // 50000
    int E = in_sizes[1];        // 800000

    char* ws = (char*)d_ws;
    size_t off = 0;
    auto alloc = [&](size_t bytes)->void*{
        void* p = ws + off; off += (bytes + 255) & ~(size_t)255; return p;
    };
    unsigned short* S1 = (unsigned short*)alloc(sizeof(unsigned short)*(size_t)N*F1);  // 12.8 MB
    unsigned short* H  = (unsigned short*)alloc(sizeof(unsigned short)*(size_t)N*F1);  // 12.8 MB
    unsigned short* S2 = (unsigned short*)alloc(sizeof(unsigned short)*(size_t)N*F2P); // 4.8 MB
    unsigned short* W1t = (unsigned short*)alloc(sizeof(unsigned short)*F1*F0);
    unsigned short* W2t = (unsigned short*)alloc(sizeof(unsigned short)*F2P*F1);
    int*   offs  = (int*)alloc(sizeof(int)*(size_t)(N+1));
    int*   cnt8  = (int*)alloc(sizeof(int)*(size_t)N*8);                 // 1.6 MB
    int*   sbase = (int*)alloc(sizeof(int)*(size_t)N*8);                 // 1.6 MB
    unsigned short* slot = (unsigned short*)alloc(sizeof(unsigned short)*(size_t)E);   // 1.6 MB
    unsigned int* edges = (unsigned int*)alloc(sizeof(unsigned int)*(size_t)E);        // 3.2 MB
    int*   gflag = (int*)alloc(sizeof(int)*64);

    int n8 = N*8;
    // weight prep + cnt8/gflag zero (grid covers both workloads)
    int prep_items = n8 > (F0*F1 + F2P*F1) ? n8 : (F0*F1 + F2P*F1);
    prep_w<<<(prep_items+255)/256,256,0,stream>>>(W1, W2, W1t, W2t, cnt8, n8, gflag);

    int gemm_nb = (N+63)/64;      // 782
    int epb = (E + gemm_nb - 1) / gemm_nb;   // 1024 edges per block
    // GEMM1 (spill-free inner-pack) + per-block hist tail
    gemm1h<<<gemm_nb,256,0,stream>>>(x, W1t, S1, N, edst, cnt8, slot, E, epb);

    // fused scan: per-chunk + cross-block prefix + shard bases (49 blocks)
    int nb = (N+1023)/1024;       // 49 <= 64 (lookback assumes this)
    scan_fused<<<nb,256,0,stream>>>(cnt8, offs, sbase, gflag, N, E);
    scatter_kernel<<<(E+255)/256,256,0,stream>>>(esrc, edst, ew, sbase, slot, edges, E);

    // layer 1 aggregation, layer 2
    agg1_kernel<<<(N+3)/4,256,0,stream>>>(S1, offs, edges, b1, H, N);
    gemm2_mfma<<<gemm_nb,256,0,stream>>>(H, W2t, S2, N);
    agg2_kernel<<<(N+3)/4,256,0,stream>>>(S2, offs, edges, b2, out, N);
}

// Round 8
// 295.152 us; speedup vs baseline: 4.3881x; 1.0554x over previous
//
#include <hip/hip_runtime.h>

// GCN 2-layer forward on MI355X (gfx950).
// out = A @ relu(A @ (x@W1) + b1) @ W2 + b2   (A = weighted edge aggregation)
// R15: hist atomics software-pipelined INTO the gemm1 phases.
//  - R14 verdict: WRITE_SIZE stayed 39MB with a provably spill-free loop =>
//    the constant ~23MB extra WRITE is the 800K returning atomics (~32B RMW
//    each, count-proportional since R8). Cost split of the 80us dispatch:
//    gemm ~16-25us, hist atomics ~50-60us, currently serialized per block.
//  - Change: issue edge k's atomicAdd right after phase k's staging barrier;
//    store its slot one phase later (1-deep software pipeline, 1 live VGPR).
//    Atomic round-trips execute under MFMA clusters + X-load stalls.
//  - Phases unrolled via inlined lambdas with literal args (no runtime-indexed
//    arrays -> no scratch). Everything else byte-identical to R14.

#define F0 512
#define F1 128
#define F2 40
#define F2P 48   // padded S2 row (bf16)

typedef short bf16x8 __attribute__((ext_vector_type(8)));
typedef float f32x4 __attribute__((ext_vector_type(4)));

// accurate RNE bf16 (weights, once per call)
static __device__ __forceinline__ unsigned short f2b(float f){
    union { float f; unsigned int u; } x; x.f = f;
    unsigned int u = x.u;
    unsigned int r = (u + 0x7fffu + ((u >> 16) & 1u)) >> 16;
    return (unsigned short)r;
}
// fast round-half-up bf16 (activations)
static __device__ __forceinline__ unsigned short f2b_fast(float f){
    return (unsigned short)((__float_as_uint(f) + 0x8000u) >> 16);
}
static __device__ __forceinline__ unsigned int pack2(float a, float b){
    unsigned int ua = __float_as_uint(a) + 0x8000u;
    unsigned int ub = __float_as_uint(b) + 0x8000u;
    return __builtin_amdgcn_perm(ub, ua, 0x07060302u);
}
static __device__ __forceinline__ bf16x8 pack8(float4 v0, float4 v1){
    union { bf16x8 v; unsigned int d[4]; } r;
    r.d[0] = pack2(v0.x, v0.y);
    r.d[1] = pack2(v0.z, v0.w);
    r.d[2] = pack2(v1.x, v1.y);
    r.d[3] = pack2(v1.z, v1.w);
    return r.v;
}
static __device__ __forceinline__ float b2f(unsigned short h){
    union { unsigned int u; float f; } x; x.u = ((unsigned int)h) << 16; return x.f;
}
// fp16 pack/unpack for edge weights (w in [0,1): rel err 2^-11)
static __device__ __forceinline__ unsigned short f2h(float f){
    union { _Float16 h; unsigned short u; } x; x.h = (_Float16)f; return x.u;
}
static __device__ __forceinline__ float h2f(unsigned short u){
    union { unsigned short u; _Float16 h; } x; x.u = u; return (float)x.h;
}

// ---------------- weight prep + cnt8/gflag zero (fused) ----------------
__global__ void prep_w(const float* __restrict__ W1, const float* __restrict__ W2,
                       unsigned short* __restrict__ W1t, unsigned short* __restrict__ W2t,
                       int* __restrict__ cnt8, int n8, int* __restrict__ gflag){
    int idx = blockIdx.x*256 + threadIdx.x;   // grid covers max(400000, 71680)
    if (idx < n8) cnt8[idx] = 0;
    if (idx < 64) gflag[idx] = 0;             // scan cross-block flags
    if (idx < F0*F1){                    // W1 [512][128] -> W1t [128][512]
        int k = idx >> 7, n = idx & 127;
        W1t[(size_t)n*F0 + k] = f2b(W1[idx]);
    } else if (idx < F0*F1 + F2P*F1){    // W2 [128][40] -> W2t [48][128]
        int j = idx - F0*F1;
        int n = j >> 7, k = j & 127;
        float v = (n < F2) ? W2[(size_t)k*F2 + n] : 0.f;
        W2t[j] = f2b(v);
    }
}

// ---- GEMM1 with hist software-pipelined into phases ----
// X[M,512]fp32 @ W1t -> S1 bf16 [M,128]. Per phase: stage B (LDS), issue one
// hist atomicAdd (edge k), 4x (load X, pack, 8 MFMA). Slot stored next phase.
__global__ __launch_bounds__(256, 3) void gemm1h(const float* __restrict__ X,
                                                 const unsigned short* __restrict__ W1t,
                                                 unsigned short* __restrict__ S1, int M,
                                                 const int* __restrict__ dst,
                                                 int* __restrict__ cnt8,
                                                 unsigned short* __restrict__ slot,
                                                 int E, int epb){
    __shared__ unsigned short sB[128*136];  // [n][136]: 272B stride -> 2-way alias (free)
    int tid = threadIdx.x;
    int wave = tid >> 6, lane = tid & 63;
    int quad = lane >> 4, l16 = lane & 15;
    int row0 = blockIdx.x * 64;
    int arow = min(row0 + wave*16 + l16, M-1);
    const float* xrow = X + (size_t)arow * F0;

    // this block's hist edges: eb + k*256, k=0..3 (epb == 1024 at N=50K,E=800K)
    int eb = blockIdx.x * epb + tid;
    int e0 = eb, e1 = eb+256, e2 = eb+512, e3 = eb+768;
    int d0 = (e0 < E) ? dst[e0] : 0;
    int d1 = (e1 < E) ? dst[e1] : 0;
    int d2 = (e2 < E) ? dst[e2] : 0;
    int d3 = (e3 < E) ? dst[e3] : 0;
    unsigned int sl = 0;

    f32x4 acc[8];
    #pragma unroll
    for (int c=0;c<8;c++) acc[c] = (f32x4){0.f,0.f,0.f,0.f};

    auto stage_b = [&](int p) __attribute__((always_inline)) {
        __syncthreads();   // prior phase's LDS reads done
        #pragma unroll
        for (int i=0;i<8;i++){
            int idx = tid + i*256;          // 0..2047
            int nn = idx >> 4, c8 = idx & 15;
            *(float4*)&sB[nn*136 + c8*8] =
                *(const float4*)&W1t[(size_t)nn*F0 + p*128 + c8*8];
        }
        __syncthreads();
    };
    auto mfma_ph = [&](int p) __attribute__((always_inline)) {
        #pragma unroll
        for (int s=0;s<4;s++){
            const float* xr = xrow + p*128 + s*32 + quad*8;
            float4 v0 = *(const float4*)(xr);
            float4 v1 = *(const float4*)(xr + 4);
            bf16x8 af = pack8(v0, v1);
            #pragma unroll
            for (int c=0;c<8;c++){
                bf16x8 b = *(bf16x8*)&sB[(c*16 + l16)*136 + s*32 + quad*8];
                acc[c] = __builtin_amdgcn_mfma_f32_16x16x32_bf16(af, b, acc[c], 0, 0, 0);
            }
        }
    };

    stage_b(0);
    if (e0 < E) sl = atomicAdd(&cnt8[d0*8 + (e0 & 7)], 1);   // overlaps phase-0 MFMAs
    mfma_ph(0);

    stage_b(1);
    if (e0 < E) slot[e0] = (unsigned short)sl;               // result ready by now
    if (e1 < E) sl = atomicAdd(&cnt8[d1*8 + (e1 & 7)], 1);
    mfma_ph(1);

    stage_b(2);
    if (e1 < E) slot[e1] = (unsigned short)sl;
    if (e2 < E) sl = atomicAdd(&cnt8[d2*8 + (e2 & 7)], 1);
    mfma_ph(2);

    stage_b(3);
    if (e2 < E) slot[e2] = (unsigned short)sl;
    if (e3 < E) sl = atomicAdd(&cnt8[d3*8 + (e3 & 7)], 1);
    mfma_ph(3);
    if (e3 < E) slot[e3] = (unsigned short)sl;

    // safety: residual edges if epb ever exceeds 1024
    int eend = min(blockIdx.x * epb + epb, E);
    for (int e = eb + 1024; e < eend; e += 256){
        int d = dst[e];
        slot[e] = (unsigned short)atomicAdd(&cnt8[d*8 + (e & 7)], 1);
    }

    // C/D: col = c*16 + l16, row = quad*4 + r
    #pragma unroll
    for (int c=0;c<8;c++){
        #pragma unroll
        for (int r=0;r<4;r++){
            int grow = row0 + wave*16 + quad*4 + r;
            if (grow < M) S1[(size_t)grow*F1 + c*16 + l16] = f2b_fast(acc[c][r]);
        }
    }
}

// ---------------- fused scan: per-chunk scan + cross-block prefix ----------------
// 49 blocks (1024 nodes each), all co-resident -> flag-spin is deadlock-free.
__global__ void scan_fused(const int* __restrict__ cnt8, int* __restrict__ offs,
                           int* __restrict__ sbase, int* __restrict__ gflag,
                           int n, int E){
    __shared__ int sd[256];
    __shared__ int s_excl;
    int tid = threadIdx.x, bid = blockIdx.x;
    int base = bid*1024 + tid*4;

    int t[4];
    int lpr[4][8];
    #pragma unroll
    for (int j=0;j<4;j++){
        int node = base+j;
        int tot = 0;
        #pragma unroll
        for (int k=0;k<8;k++) lpr[j][k] = 0;
        if (node < n){
            int4 c0 = *(const int4*)&cnt8[(size_t)node*8];
            int4 c1 = *(const int4*)&cnt8[(size_t)node*8+4];
            int run;
            lpr[j][0] = 0;   run  = c0.x;
            lpr[j][1] = run; run += c0.y;
            lpr[j][2] = run; run += c0.z;
            lpr[j][3] = run; run += c0.w;
            lpr[j][4] = run; run += c1.x;
            lpr[j][5] = run; run += c1.y;
            lpr[j][6] = run; run += c1.z;
            lpr[j][7] = run; run += c1.w;
            tot = run;
        }
        t[j] = tot;
    }
    int v1 = t[0], v2 = t[0]+t[1], v3 = v2+t[2];
    int s = v3 + t[3];
    sd[tid] = s; __syncthreads();
    for (int off=1; off<256; off<<=1){
        int tt = (tid>=off) ? sd[tid-off] : 0;
        __syncthreads();
        sd[tid] += tt;
        __syncthreads();
    }
    int excl = sd[tid] - s;
    int btot = sd[255];

    // publish this block's total (value+1 so 0 == not-ready)
    if (tid == 0)
        __hip_atomic_store(&gflag[bid], btot + 1, __ATOMIC_RELEASE, __HIP_MEMORY_SCOPE_AGENT);
    // wave 0: gather predecessors' totals (bid <= 48 < 64 lanes)
    if (tid < 64){
        int v = 0;
        if (tid < bid){
            int g;
            do {
                g = __hip_atomic_load(&gflag[tid], __ATOMIC_ACQUIRE, __HIP_MEMORY_SCOPE_AGENT);
                if (g == 0) __builtin_amdgcn_s_sleep(1);
            } while (g == 0);
            v = g - 1;
        }
        #pragma unroll
        for (int o=1; o<64; o<<=1) v += __shfl_xor(v, o);
        if (tid == 0) s_excl = v;
    }
    __syncthreads();

    int node_off[4] = {0, v1, v2, v3};
    int gexcl = s_excl + excl;
    #pragma unroll
    for (int j=0;j<4;j++){
        int node = base+j;
        if (node < n){
            int o = gexcl + node_off[j];
            offs[node] = o;
            int4 s0, s1;
            s0.x = o + lpr[j][0]; s0.y = o + lpr[j][1];
            s0.z = o + lpr[j][2]; s0.w = o + lpr[j][3];
            s1.x = o + lpr[j][4]; s1.y = o + lpr[j][5];
            s1.z = o + lpr[j][6]; s1.w = o + lpr[j][7];
            *(int4*)&sbase[(size_t)node*8]   = s0;
            *(int4*)&sbase[(size_t)node*8+4] = s1;
        }
    }
    if (bid == 0 && tid == 0) offs[n] = E;
}

// atomic-free scatter: pos = sbase[d][shard] + saved slot
__global__ void scatter_kernel(const int* __restrict__ src, const int* __restrict__ dst,
                               const float* __restrict__ w,
                               const int* __restrict__ sbase,
                               const unsigned short* __restrict__ slot,
                               unsigned int* __restrict__ edges, int E){
    int e = blockIdx.x*256+threadIdx.x;
    if (e<E){
        int d = dst[e];
        int pos = sbase[d*8 + (e & 7)] + (int)slot[e];
        edges[pos] = ((unsigned int)src[e] << 16) | (unsigned int)f2h(w[e]);
    }
}

// ---- agg1: H = relu(A@S1 + b1) bf16, F=128 (unchanged) ----
__global__ void agg1_kernel(const unsigned short* __restrict__ S1, const int* __restrict__ offs,
                            const unsigned int* __restrict__ edges,
                            const float* __restrict__ b1, unsigned short* __restrict__ H, int n){
    int node = blockIdx.x*4 + (threadIdx.x >> 6);   // one wave per node
    int lane = threadIdx.x & 63;
    if (node >= n) return;
    int half = lane >> 5, fl = lane & 31;
    int e0 = offs[node], e1 = offs[node+1];
    double a0=0.0, a1=0.0, a2=0.0, a3=0.0;
    int e = e0;
    for (; e+8 <= e1; e += 8){
        unsigned int rA = edges[e   + half];
        unsigned int rB = edges[e+2 + half];
        unsigned int rC = edges[e+4 + half];
        unsigned int rD = edges[e+6 + half];
        ushort4 vA = *(const ushort4*)&S1[((size_t)(rA>>16))*F1 + fl*4];
        ushort4 vB = *(const ushort4*)&S1[((size_t)(rB>>16))*F1 + fl*4];
        ushort4 vC = *(const ushort4*)&S1[((size_t)(rC>>16))*F1 + fl*4];
        ushort4 vD = *(const ushort4*)&S1[((size_t)(rD>>16))*F1 + fl*4];
        double wA = h2f((unsigned short)rA), wB = h2f((unsigned short)rB);
        double wC = h2f((unsigned short)rC), wD = h2f((unsigned short)rD);
        a0 += wA*b2f(vA.x) + wB*b2f(vB.x) + wC*b2f(vC.x) + wD*b2f(vD.x);
        a1 += wA*b2f(vA.y) + wB*b2f(vB.y) + wC*b2f(vC.y) + wD*b2f(vD.y);
        a2 += wA*b2f(vA.z) + wB*b2f(vB.z) + wC*b2f(vC.z) + wD*b2f(vD.z);
        a3 += wA*b2f(vA.w) + wB*b2f(vB.w) + wC*b2f(vC.w) + wD*b2f(vD.w);
    }
    for (; e < e1; e += 2){
        int ee = e + half;
        if (ee < e1){
            unsigned int r = edges[ee];
            ushort4 v = *(const ushort4*)&S1[((size_t)(r>>16))*F1 + fl*4];
            double w = h2f((unsigned short)r);
            a0 += w*b2f(v.x); a1 += w*b2f(v.y); a2 += w*b2f(v.z); a3 += w*b2f(v.w);
        }
    }
    a0 += __shfl_down(a0, 32);
    a1 += __shfl_down(a1, 32);
    a2 += __shfl_down(a2, 32);
    a3 += __shfl_down(a3, 32);
    if (lane < 32){
        float4 bb = *(const float4*)&b1[fl*4];
        float o0 = (float)(a0 + (double)bb.x);
        float o1 = (float)(a1 + (double)bb.y);
        float o2 = (float)(a2 + (double)bb.z);
        float o3 = (float)(a3 + (double)bb.w);
        o0 = o0>0.f?o0:0.f; o1 = o1>0.f?o1:0.f;
        o2 = o2>0.f?o2:0.f; o3 = o3>0.f?o3:0.f;
        union { ushort4 v; unsigned int d[2]; } o;
        o.d[0] = pack2(o0, o1);
        o.d[1] = pack2(o2, o3);
        *(ushort4*)&H[(size_t)node*F1 + fl*4] = o.v;
    }
}

// ---- GEMM2: H bf16 [M,128] @ W2t -> S2 bf16 [M,48] (unchanged) ----
__global__ __launch_bounds__(256) void gemm2_mfma(const unsigned short* __restrict__ H,
                                                  const unsigned short* __restrict__ W2t,
                                                  unsigned short* __restrict__ S2, int M){
    __shared__ unsigned short sB[48][136];
    int tid = threadIdx.x;
    int wave = tid >> 6, lane = tid & 63;
    int quad = lane >> 4, l16 = lane & 15;
    for (int i = tid; i < 48*16; i += 256){
        int nn = i >> 4, p = i & 15;
        *(float4*)&sB[nn][p*8] = *(const float4*)&W2t[(size_t)nn*F1 + p*8];
    }
    int row0 = blockIdx.x * 64;
    int myrow = row0 + wave*16 + l16;
    int arow = min(myrow, M-1);
    const unsigned short* hrow = H + (size_t)arow * F1;
    bf16x8 a[4];
    #pragma unroll
    for (int ks=0; ks<4; ks++) a[ks] = *(const bf16x8*)(hrow + ks*32 + quad*8);
    __syncthreads();
    f32x4 acc[3];
    #pragma unroll
    for (int c=0;c<3;c++) acc[c] = (f32x4){0.f,0.f,0.f,0.f};
    #pragma unroll
    for (int ks=0; ks<4; ks++){
        #pragma unroll
        for (int c=0;c<3;c++){
            bf16x8 b = *(bf16x8*)&sB[c*16 + l16][ks*32 + quad*8];
            acc[c] = __builtin_amdgcn_mfma_f32_16x16x32_bf16(a[ks], b, acc[c], 0, 0, 0);
        }
    }
    #pragma unroll
    for (int c=0;c<3;c++){
        #pragma unroll
        for (int r=0;r<4;r++){
            int grow = row0 + wave*16 + quad*4 + r;
            if (grow < M) S2[(size_t)grow*F2P + c*16 + l16] = f2b_fast(acc[c][r]);
        }
    }
}

// ---- agg2: out = A@S2 + b2, F=40 (unchanged) ----
__global__ void agg2_kernel(const unsigned short* __restrict__ S2, const int* __restrict__ offs,
                            const unsigned int* __restrict__ edges,
                            const float* __restrict__ b2, float* __restrict__ out, int n){
    int node = blockIdx.x*4 + (threadIdx.x >> 6);  // one wave per node
    int lane = threadIdx.x & 63;
    if (node >= n) return;
    int grp = lane >> 4, gl = lane & 15;
    bool act = gl < 10;
    int e0 = offs[node], e1 = offs[node+1];
    double a0=0.0, a1=0.0, a2=0.0, a3=0.0;
    for (int e = e0; e < e1; e += 4){
        int ee = e + grp;
        if (ee < e1 && act){
            unsigned int r = edges[ee];
            ushort4 v = *(const ushort4*)&S2[((size_t)(r>>16))*F2P + gl*4];
            double w = h2f((unsigned short)r);
            a0 += w*b2f(v.x); a1 += w*b2f(v.y); a2 += w*b2f(v.z); a3 += w*b2f(v.w);
        }
    }
    a0 += __shfl_down(a0, 32); a0 += __shfl_down(a0, 16);
    a1 += __shfl_down(a1, 32); a1 += __shfl_down(a1, 16);
    a2 += __shfl_down(a2, 32); a2 += __shfl_down(a2, 16);
    a3 += __shfl_down(a3, 32); a3 += __shfl_down(a3, 16);
    if (lane < 10){
        float4 bb = *(const float4*)&b2[lane*4];
        float4 o;
        o.x = (float)(a0 + (double)bb.x);
        o.y = (float)(a1 + (double)bb.y);
        o.z = (float)(a2 + (double)bb.z);
        o.w = (float)(a3 + (double)bb.w);
        *(float4*)&out[(size_t)node*F2 + lane*4] = o;
    }
}

extern "C" void kernel_launch(void* const* d_in, const int* in_sizes, int n_in,
                              void* d_out, int out_size, void* d_ws, size_t ws_size,
                              hipStream_t stream){
    const float* x    = (const float*)d_in[0];
    const int*   esrc = (const int*)d_in[1];
    const int*   edst = (const int*)d_in[2];
    const float* ew   = (const float*)d_in[3];
    const float* W1   = (const float*)d_in[4];
    const float* b1   = (const float*)d_in[5];
    const float* W2   = (const float*)d_in[6];
    const float* b2   = (const float*)d_in[7];
    float* out = (float*)d_out;
    int N = in_sizes[0] / F0;   // 50000
    int E = in_sizes[1];        // 800000

    char* ws = (char*)d_ws;
    size_t off = 0;
    auto alloc = [&](size_t bytes)->void*{
        void* p = ws + off; off += (bytes + 255) & ~(size_t)255; return p;
    };
    unsigned short* S1 = (unsigned short*)alloc(sizeof(unsigned short)*(size_t)N*F1);  // 12.8 MB
    unsigned short* H  = (unsigned short*)alloc(sizeof(unsigned short)*(size_t)N*F1);  // 12.8 MB
    unsigned short* S2 = (unsigned short*)alloc(sizeof(unsigned short)*(size_t)N*F2P); // 4.8 MB
    unsigned short* W1t = (unsigned short*)alloc(sizeof(unsigned short)*F1*F0);
    unsigned short* W2t = (unsigned short*)alloc(sizeof(unsigned short)*F2P*F1);
    int*   offs  = (int*)alloc(sizeof(int)*(size_t)(N+1));
    int*   cnt8  = (int*)alloc(sizeof(int)*(size_t)N*8);                 // 1.6 MB
    int*   sbase = (int*)alloc(sizeof(int)*(size_t)N*8);                 // 1.6 MB
    unsigned short* slot = (unsigned short*)alloc(sizeof(unsigned short)*(size_t)E);   // 1.6 MB
    unsigned int* edges = (unsigned int*)alloc(sizeof(unsigned int)*(size_t)E);        // 3.2 MB
    int*   gflag = (int*)alloc(sizeof(int)*64);

    int n8 = N*8;
    // weight prep + cnt8/gflag zero (grid covers both workloads)
    int prep_items = n8 > (F0*F1 + F2P*F1) ? n8 : (F0*F1 + F2P*F1);
    prep_w<<<(prep_items+255)/256,256,0,stream>>>(W1, W2, W1t, W2t, cnt8, n8, gflag);

    int gemm_nb = (N+63)/64;      // 782
    int epb = (E + gemm_nb - 1) / gemm_nb;   // 1024 edges per block
    // GEMM1 with hist pipelined into phases
    gemm1h<<<gemm_nb,256,0,stream>>>(x, W1t, S1, N, edst, cnt8, slot, E, epb);

    // fused scan: per-chunk + cross-block prefix + shard bases (49 blocks)
    int nb = (N+1023)/1024;       // 49 <= 64 (lookback assumes this)
    scan_fused<<<nb,256,0,stream>>>(cnt8, offs, sbase, gflag, N, E);
    scatter_kernel<<<(E+255)/256,256,0,stream>>>(esrc, edst, ew, sbase, slot, edges, E);

    // layer 1 aggregation, layer 2
    agg1_kernel<<<(N+3)/4,256,0,stream>>>(S1, offs, edges, b1, H, N);
    gemm2_mfma<<<gemm_nb,256,0,stream>>>(H, W2t, S2, N);
    agg2_kernel<<<(N+3)/4,256,0,stream>>>(S2, offs, edges, b2, out, N);
}